// Round 7
// baseline (132.649 us; speedup 1.0000x reference)
//
#include <hip/hip_runtime.h>
#include <math.h>

#define S_LEN 1024
#define D_DIM 64
#define NBH   16
#define RPB   14
#define NSB   74           // ceil(1024/14)

typedef unsigned short ushort_t;
typedef unsigned int uint_t;
typedef __attribute__((ext_vector_type(8))) _Float16 half8;  // 8 f16 (4 VGPRs)
typedef __attribute__((ext_vector_type(4))) short short4v;   // 8 B
typedef __attribute__((ext_vector_type(4))) float f32x4;

__device__ __forceinline__ ushort_t f16bits(float x) {
    _Float16 h = (_Float16)x;                 // RNE
    ushort_t b;
    __builtin_memcpy(&b, &h, 2);
    return b;
}
__device__ __forceinline__ float uniform_f(float x) {
    return __int_as_float(__builtin_amdgcn_readfirstlane(__float_as_int(x)));
}
__device__ __forceinline__ float fast_exp2(float x) {
#if __has_builtin(__builtin_amdgcn_exp2f)
    return __builtin_amdgcn_exp2f(x);         // v_exp_f32 (2^x)
#else
    return exp2f(x);
#endif
}
__device__ __forceinline__ half8 mk8(uint2 a, uint2 b) {
    union { uint_t u[4]; half8 h; } c;
    c.u[0] = a.x; c.u[1] = a.y; c.u[2] = b.x; c.u[3] = b.y;
    return c.h;
}
// dpT swizzle: row = 16 halfs = 4 units of 8B; unit p stored at (p+(row>>2))&3.
__device__ __forceinline__ int swz(int row, int unit) {
    return (row << 4) + (((unit + (row >> 2)) & 3) << 2);
}

// ------------------------------ Prep (unchanged) -----------------------------
__global__ __launch_bounds__(256) void prep(
    const float* __restrict__ k, const float* __restrict__ v,
    const int* __restrict__ mask, const float* __restrict__ conv_w,
    ushort_t* __restrict__ kh, ushort_t* __restrict__ vh,
    unsigned* __restrict__ mw, ushort_t* __restrict__ wtab)
{
    __shared__ float Ls[64][65];
    const int tid = threadIdx.x;
    const int bx = blockIdx.x;
    if (bx < 512) {
        const int gid  = bx * 256 + tid;          // 0..131071
        const int bh   = gid >> 13;
        const int tile = (gid >> 7) & 63;
        const int ch   = (gid >> 6) & 1;
        const int lane = gid & 63;
        const int quad = lane >> 4, t15 = lane & 15;
        const float* src = k + ((size_t)bh * S_LEN + tile * 16 + t15) * D_DIM
                             + ch * 32 + quad * 8;
        float x[8];
        *(float4*)(x + 0) = *(const float4*)(src);
        *(float4*)(x + 4) = *(const float4*)(src + 4);
        ushort_t hv[8];
        #pragma unroll
        for (int i = 0; i < 8; ++i) hv[i] = f16bits(x[i] * 0.125f);
        *(short4v*)(kh + (size_t)gid * 8)     = *(short4v*)(hv);
        *(short4v*)(kh + (size_t)gid * 8 + 4) = *(short4v*)(hv + 4);
    } else if (bx < 768) {
        const int bi = bx - 512;
        const int tt = bi & 15, bh = bi >> 4;
        const float* vb = v + ((size_t)bh * S_LEN + tt * 64) * D_DIM;
        #pragma unroll
        for (int p = 0; p < 4; ++p) {
            int idx = p * 1024 + tid * 4;
            int r = idx >> 6, c = idx & 63;
            float4 x = *(const float4*)(vb + r * 64 + c);
            Ls[r][c] = x.x; Ls[r][c+1] = x.y; Ls[r][c+2] = x.z; Ls[r][c+3] = x.w;
        }
        __syncthreads();
        const int d = tid >> 2, c0 = (tid & 3) * 16;
        ushort_t hi[16];
        #pragma unroll
        for (int j = 0; j < 16; ++j) hi[j] = f16bits(Ls[c0 + j][d]);
        const int tb0 = tt * 8 + (c0 >> 3);
        const size_t o0 = (((size_t)bh * 128 + tb0) * 64 + d) * 8;
        const size_t o1 = (((size_t)bh * 128 + tb0 + 1) * 64 + d) * 8;
        *(short4v*)(vh + o0)     = *(short4v*)(hi);
        *(short4v*)(vh + o0 + 4) = *(short4v*)(hi + 4);
        *(short4v*)(vh + o1)     = *(short4v*)(hi + 8);
        *(short4v*)(vh + o1 + 4) = *(short4v*)(hi + 12);
    } else if (bx < 1024) {
        const int gid = (bx - 768) * 256 + tid;    // 0..65535
        const int row = gid >> 5, wd = gid & 31;   // row = b*1024+s
        const int4* mp = (const int4*)(mask + (size_t)row * 1024 + wd * 32);
        unsigned bits = 0;
        #pragma unroll
        for (int p = 0; p < 8; ++p) {
            int4 qv = mp[p];
            bits |= (qv.x != 0 ? 1u : 0u) << (p * 4 + 0);
            bits |= (qv.y != 0 ? 1u : 0u) << (p * 4 + 1);
            bits |= (qv.z != 0 ? 1u : 0u) << (p * 4 + 2);
            bits |= (qv.w != 0 ? 1u : 0u) << (p * 4 + 3);
        }
        mw[(size_t)row * 32 + wd] = bits;
    } else {
        // Banded weight table; value w[r-o+1][dc] is symmetric in the
        // (l&15, k&15) roles -> serves the swapped B-side use unchanged.
        if (tid < 64) {
            const int o = tid & 15, qd = tid >> 4;
            half8* wt = (half8*)wtab;
            #pragma unroll
            for (int f = 0; f < 4; ++f) {
                half8 fr0 = {}, fr1 = {}, fr2 = {};
                #pragma unroll
                for (int i = 0; i < 8; ++i) {
                    const int kk = qd * 8 + i;
                    const int r  = kk & 15;
                    const bool hiK = kk < 16;
                    #pragma unroll
                    for (int dr = 0; dr < 3; ++dr) {
                        if (r - o == dr - 1) {
                            const float w0 = conv_w[f*9 + dr*3 + 0];
                            const float w1 = conv_w[f*9 + dr*3 + 1];
                            const float w2 = conv_w[f*9 + dr*3 + 2];
                            const _Float16 w0h = (_Float16)w0;
                            const _Float16 w1h = (_Float16)w1;
                            const _Float16 w2h = (_Float16)w2;
                            const _Float16 w0l = (_Float16)(w0 - (float)w0h);
                            const _Float16 w1l = (_Float16)(w1 - (float)w1h);
                            const _Float16 w2l = (_Float16)(w2 - (float)w2h);
                            fr0[i] = hiK ? w0h : w1h;
                            fr1[i] = hiK ? w0l : w1l;
                            fr2[i] = hiK ? w2h : w2l;
                        }
                    }
                }
                wt[(f*64 + tid)*3 + 0] = fr0;
                wt[(f*64 + tid)*3 + 1] = fr1;
                wt[(f*64 + tid)*3 + 2] = fr2;
            }
        }
    }
}

// ---------- Fused: QK^T -> swapped MFMA conv -> in-register P -> PV ----------
// grid (74, 16), block 512 = 8 waves. LDS ~35.6 KB -> 4 blocks/CU.
// SWAPPED conv: out^T = sum_dc X_dc^T @ W_dc^T; A-frag = dpT rows (addressing
// byte-identical to R5), W = B-operand (same wtab by band symmetry).
// C-frag: lane (m,quad) holds P[s=m][t=Tg*16+4*quad+r] IN REGISTERS.
// PV swapped: O^T = V^T * P^T. P^T B-frag gathered from registers; a source
// lane serves TWO callers needing DIFFERENT T (quad1 needs 2kt from q'2/3,
// quad2 needs 2kt+1 from q'0/1) -> one bpermute per slot CANNOT serve both
// (R6 bug). Fix: gather BOTH PK[2kt] and PK[2kt+1] (8 bpermute/kt) and
// select per caller with (quad>>1).
// NO P LDS round-trip, no mid-kernel barriers; 2 barriers around the final
// 8-way partial reduce (partials alias sBuf after dpT is dead).
__global__ __launch_bounds__(512, 3) void fused_qk_conv_av(
    const float* __restrict__ q,
    const ushort_t* __restrict__ kh, const unsigned* __restrict__ mw,
    const ushort_t* __restrict__ vh, const ushort_t* __restrict__ wtab,
    const float* __restrict__ conv_b,
    const float* __restrict__ lin_w, const float* __restrict__ lin_b,
    float* __restrict__ out)
{
    __shared__ __align__(16) ushort_t sBuf[16512]; // 33.0 KB; dpT, then O-partials
    __shared__ unsigned mbT[32][16];               // 2 KB
    __shared__ float rsP[8][16];                   // 512 B rowsum partials

    const int st = blockIdx.x, bh = blockIdx.y;
    const int s0 = st * RPB;
    const int b  = bh >> 3;
    const int tid = threadIdx.x;
    const int wave = tid >> 6, lane = tid & 63;
    const int m = lane & 15, quad = lane >> 4;

    // mask bits -> mbT[word][s-row o]; wave w writes words 4w..4w+3 = exactly
    // the words it reads in Phase B -> wave-private, no barrier.
    {
        const int wd = tid >> 4, o = tid & 15;
        const int s = s0 - 1 + o;
        mbT[wd][o] = (s >= 0 && s < S_LEN)
                   ? mw[((size_t)b * S_LEN + s) * 32 + wd] : 0u;
    }
    // pad rows written by their READER wave (wave-private)
    if (wave == 0 && lane < 16) sBuf[(1    << 4) + lane] = 0;  // t = -1
    if (wave == 7 && lane < 16) sBuf[(1026 << 4) + lane] = 0;  // t = 1024

    // ---------------- Phase A: QK into LDS, transposed+swizzled -------------
    const int sA = s0 - 1 + m;
    const int sQ = sA < 0 ? 0 : (sA > S_LEN - 1 ? S_LEN - 1 : sA);
    const float* qp = q + ((size_t)bh * S_LEN + sQ) * D_DIM + quad * 8;
    float qa[16];
    *(float4*)(qa + 0)  = *(const float4*)(qp + 0);
    *(float4*)(qa + 4)  = *(const float4*)(qp + 4);
    *(float4*)(qa + 8)  = *(const float4*)(qp + 32);
    *(float4*)(qa + 12) = *(const float4*)(qp + 36);
    half8 AH0, AH1;
    #pragma unroll
    for (int i = 0; i < 8; ++i) {
        AH0[i] = (_Float16)qa[i];          // 1/8 scale folded into kh
        AH1[i] = (_Float16)qa[8 + i];
    }

    #pragma unroll
    for (int tt = 0; tt < 8; ++tt) {
        const int tile = wave * 8 + tt;
        const size_t kb = (((size_t)bh * 64 + tile) * 128 + lane) * 8;
        half8 KH0 = *(const half8*)(kh + kb);
        half8 KH1 = *(const half8*)(kh + kb + 512);
        f32x4 a = {0.f, 0.f, 0.f, 0.f};
        a = __builtin_amdgcn_mfma_f32_16x16x32_f16(AH0, KH0, a, 0, 0, 0);
        a = __builtin_amdgcn_mfma_f32_16x16x32_f16(AH1, KH1, a, 0, 0, 0);
        ushort_t t4[4];
        #pragma unroll
        for (int r = 0; r < 4; ++r) {
            const int s = s0 - 1 + quad * 4 + r;
            const float v = (s >= 0 && s < S_LEN) ? a[r] : 0.f;
            t4[r] = f16bits(v);
        }
        uint2 wv2;
        wv2.x = (uint_t)t4[0] | ((uint_t)t4[1] << 16);
        wv2.y = (uint_t)t4[2] | ((uint_t)t4[3] << 16);
        *(uint2*)&sBuf[swz(tile * 16 + m + 2, quad)] = wv2;
    }
    // halo tiles: full compute, boundary-column write only
    #pragma unroll
    for (int hsel = 0; hsel < 2; ++hsel) {
        const int tile = hsel ? (wave * 8 + 8) : (wave * 8 - 1);
        const int wantM = hsel ? 0 : 15;
        if (tile >= 0 && tile < 64) {
            const size_t kb = (((size_t)bh * 64 + tile) * 128 + lane) * 8;
            half8 KH0 = *(const half8*)(kh + kb);
            half8 KH1 = *(const half8*)(kh + kb + 512);
            f32x4 a = {0.f, 0.f, 0.f, 0.f};
            a = __builtin_amdgcn_mfma_f32_16x16x32_f16(AH0, KH0, a, 0, 0, 0);
            a = __builtin_amdgcn_mfma_f32_16x16x32_f16(AH1, KH1, a, 0, 0, 0);
            if (m == wantM) {
                ushort_t t4[4];
                #pragma unroll
                for (int r = 0; r < 4; ++r) {
                    const int s = s0 - 1 + quad * 4 + r;
                    const float v = (s >= 0 && s < S_LEN) ? a[r] : 0.f;
                    t4[r] = f16bits(v);
                }
                uint2 wv2;
                wv2.x = (uint_t)t4[0] | ((uint_t)t4[1] << 16);
                wv2.y = (uint_t)t4[2] | ((uint_t)t4[3] << 16);
                *(uint2*)&sBuf[swz(tile * 16 + m + 2, quad)] = wv2;
            }
        }
    }

    const float L2E = 1.44269504088896341f;
    const float lbE = uniform_f(lin_b[0] * L2E);

    // ---------------- Phase B: swapped MFMA conv; P stays in registers ------
    const int u0 = (quad & 1) << 1;
    const int rB = m + 1 + (quad >> 1);
    const bool act = (m >= 1) && (m <= RPB) && (s0 - 1 + m < S_LEN);
    uint_t PK[8][2];          // packed f16 P[s=m][t=Tg*16+4q+{0..3}]
    float rs = 0.f;
    #pragma unroll
    for (int T = 0; T < 8; ++T) {
        const int Tg = wave * 8 + T;
        const int base = Tg * 16;
        half8 A01 = mk8(*(const uint2*)&sBuf[swz(base + rB, u0)],
                        *(const uint2*)&sBuf[swz(base + rB, u0 + 1)]);
        half8 A22 = mk8(*(const uint2*)&sBuf[swz(base + m + 3, u0)],
                        *(const uint2*)&sBuf[swz(base + m + 3, u0 + 1)]);
        float pre[4] = {lbE, lbE, lbE, lbE};
        #pragma unroll 1
        for (int f = 0; f < 4; ++f) {
            const float cbf = uniform_f(conv_b[f]);
            const float lwf = lin_w[f];
            const float af  = uniform_f(0.505f * lwf * L2E);
            const float bf2 = uniform_f(0.495f * lwf * L2E);
            const half8* wp = (const half8*)wtab + (f * 64 + lane) * 3;
            const half8 W0 = wp[0];
            const half8 W1 = wp[1];
            const half8 W2 = wp[2];
            f32x4 a = {0.f, 0.f, 0.f, 0.f};
            a = __builtin_amdgcn_mfma_f32_16x16x32_f16(A01, W0, a, 0, 0, 0);
            a = __builtin_amdgcn_mfma_f32_16x16x32_f16(A01, W1, a, 0, 0, 0);
            a = __builtin_amdgcn_mfma_f32_16x16x32_f16(A22, W2, a, 0, 0, 0);
            #pragma unroll
            for (int r = 0; r < 4; ++r) {
                const float y = a[r] + cbf;
                pre[r] = fmaf(af, y, pre[r]);
                pre[r] = fmaf(bf2, fabsf(y), pre[r]);   // abs = VOP3 modifier
            }
        }
        const unsigned mword = mbT[Tg >> 1][m];
        const int bb = ((Tg & 1) << 4) + quad * 4;
        float pv[4];
        #pragma unroll
        for (int r = 0; r < 4; ++r) {
            const bool keep = act && ((mword >> (bb + r)) & 1u);
            pv[r] = fast_exp2(keep ? pre[r] : -1e30f);
            rs += pv[r];
        }
        PK[T][0] = (uint_t)f16bits(pv[0]) | ((uint_t)f16bits(pv[1]) << 16);
        PK[T][1] = (uint_t)f16bits(pv[2]) | ((uint_t)f16bits(pv[3]) << 16);
    }
    // rowsum: cross-quad reduce (lanes sharing m), publish per-wave partial
    rs += __shfl_xor(rs, 16);
    rs += __shfl_xor(rs, 32);
    if (quad == 0) rsP[wave][m] = rs;

    // ---------------- Phase C: PV as O^T = V^T * P^T (registers only) -------
    // Caller lane (m,quad), slot i: t = wave*128+kt*32+quad*8+i. Source:
    // lane (m, q' = 2*(quad&1)+(i>>2)), PK[2kt+(quad>>1)][(i>>1)&1], half i&1.
    // Gather both T candidates, select by quad>>1 (fixes R6 swap bug).
    f32x4 acc[4] = {{0,0,0,0},{0,0,0,0},{0,0,0,0},{0,0,0,0}};
    const int addrA = (m + 32 * (quad & 1)) * 4;
    const int addrB = addrA + 64;
    const bool selHi = (quad & 2) != 0;
    #pragma unroll
    for (int kt = 0; kt < 4; ++kt) {
        const int e0 = (int)PK[2*kt][0],     e1 = (int)PK[2*kt][1];
        const int f0 = (int)PK[2*kt + 1][0], f1 = (int)PK[2*kt + 1][1];
        const uint_t gA0 = (uint_t)__builtin_amdgcn_ds_bpermute(addrA, e0);
        const uint_t gA1 = (uint_t)__builtin_amdgcn_ds_bpermute(addrA, e1);
        const uint_t hA0 = (uint_t)__builtin_amdgcn_ds_bpermute(addrA, f0);
        const uint_t hA1 = (uint_t)__builtin_amdgcn_ds_bpermute(addrA, f1);
        const uint_t gB0 = (uint_t)__builtin_amdgcn_ds_bpermute(addrB, e0);
        const uint_t gB1 = (uint_t)__builtin_amdgcn_ds_bpermute(addrB, e1);
        const uint_t hB0 = (uint_t)__builtin_amdgcn_ds_bpermute(addrB, f0);
        const uint_t hB1 = (uint_t)__builtin_amdgcn_ds_bpermute(addrB, f1);
        union { uint_t u[4]; half8 h; } pf;
        pf.u[0] = selHi ? hA0 : gA0;
        pf.u[1] = selHi ? hA1 : gA1;
        pf.u[2] = selHi ? hB0 : gB0;
        pf.u[3] = selHi ? hB1 : gB1;
        const size_t tb = (size_t)bh * 128 + wave * 16 + kt * 4 + quad;
        #pragma unroll
        for (int dt = 0; dt < 4; ++dt) {
            half8 vv = *(const half8*)(vh + (tb * 64 + dt * 16 + m) * 8);
            acc[dt] = __builtin_amdgcn_mfma_f32_16x16x32_f16(vv, pf.h, acc[dt], 0, 0, 0);
        }
    }

    __syncthreads();   // all waves done with dpT -> sBuf reusable as partials

    // O-partials: pbuf[w][s=m][d] f32, d XOR-swizzled by (m&7)<<2
    float* pbuf = (float*)sBuf;
    #pragma unroll
    for (int dt = 0; dt < 4; ++dt) {
        #pragma unroll
        for (int r = 0; r < 4; ++r) {
            const int d = dt * 16 + quad * 4 + r;
            pbuf[(wave * 16 + m) * 64 + (d ^ ((m & 7) << 2))] = acc[dt][r];
        }
    }
    __syncthreads();

    // ---------------- Reduce: sum 8 partials, divide, store -----------------
    #pragma unroll
    for (int e = 0; e < 2; ++e) {
        const int id = tid + e * 512;
        if (id < 896) {
            const int o = (id >> 6) + 1;       // 1..14
            const int d = id & 63;
            const int dx = d ^ ((o & 7) << 2);
            float sum = 0.f, ls = 0.f;
            #pragma unroll
            for (int w = 0; w < 8; ++w) {
                sum += pbuf[(w * 16 + o) * 64 + dx];
                ls  += rsP[w][o];
            }
            const int s = s0 - 1 + o;
            if (s < S_LEN)
                out[((size_t)bh * S_LEN + s) * D_DIM + d] = sum / ls;
        }
    }
}

extern "C" void kernel_launch(void* const* d_in, const int* in_sizes, int n_in,
                              void* d_out, int out_size, void* d_ws, size_t ws_size,
                              hipStream_t stream) {
    const float* q      = (const float*)d_in[0];
    const float* k      = (const float*)d_in[1];
    const float* v      = (const float*)d_in[2];
    const int*   mask   = (const int*)d_in[3];
    const float* conv_w = (const float*)d_in[4];
    const float* conv_b = (const float*)d_in[5];
    const float* lin_w  = (const float*)d_in[6];
    const float* lin_b  = (const float*)d_in[7];
    float* out = (float*)d_out;

    char* wsb = (char*)d_ws;
    const size_t MB = 1024 * 1024;
    ushort_t* kh   = (ushort_t*)(wsb + 0 * MB);          // 2 MiB
    ushort_t* vh   = (ushort_t*)(wsb + 2 * MB);          // 2 MiB
    unsigned* mw   = (unsigned*)(wsb + 4 * MB);          // 256 KiB
    ushort_t* wtab = (ushort_t*)(wsb + 4 * MB + 256 * 1024);  // 12 KiB

    prep<<<dim3(1025), 256, 0, stream>>>(k, v, mask, conv_w, kh, vh, mw, wtab);
    fused_qk_conv_av<<<dim3(NSB, NBH), 512, 0, stream>>>(
        q, kh, mw, vh, wtab, conv_b, lin_w, lin_b, out);
}

// Round 8
// 118.020 us; speedup vs baseline: 1.1240x; 1.1240x over previous
//
#include <hip/hip_runtime.h>
#include <math.h>

#define S_LEN 1024
#define D_DIM 64
#define NBH   16
#define RPB   14
#define NSB   74           // ceil(1024/14)

typedef unsigned short ushort_t;
typedef unsigned int uint_t;
typedef __attribute__((ext_vector_type(8))) _Float16 half8;  // 8 f16 (4 VGPRs)
typedef __attribute__((ext_vector_type(2))) _Float16 h2;
typedef __attribute__((ext_vector_type(4))) short short4v;   // 8 B
typedef __attribute__((ext_vector_type(4))) float f32x4;

__device__ __forceinline__ ushort_t f16bits(float x) {
    _Float16 h = (_Float16)x;                 // RNE
    ushort_t b;
    __builtin_memcpy(&b, &h, 2);
    return b;
}
__device__ __forceinline__ float uniform_f(float x) {
    return __int_as_float(__builtin_amdgcn_readfirstlane(__float_as_int(x)));
}
__device__ __forceinline__ float fast_exp2(float x) {
#if __has_builtin(__builtin_amdgcn_exp2f)
    return __builtin_amdgcn_exp2f(x);         // v_exp_f32 (2^x)
#else
    return exp2f(x);
#endif
}

// ------------------------------ Prep ----------------------------------------
// blocks [0,512):    K * 0.125 -> f16 QK B-frag tiled layout (16B stores)
//                    (1/sqrt(D) folded into K so Phase A skips the scale)
// blocks [512,768):  V transpose -> f16 PV B-frag tiled layout
// blocks [768,1024): mask bit-pack, thread-per-word
__global__ __launch_bounds__(256) void prep(
    const float* __restrict__ k, const float* __restrict__ v,
    const int* __restrict__ mask,
    ushort_t* __restrict__ kh, ushort_t* __restrict__ vh,
    unsigned* __restrict__ mw)
{
    __shared__ float Ls[64][65];
    const int tid = threadIdx.x;
    const int bx = blockIdx.x;
    if (bx < 512) {
        const int gid  = bx * 256 + tid;          // 0..131071
        const int bh   = gid >> 13;
        const int tile = (gid >> 7) & 63;
        const int ch   = (gid >> 6) & 1;
        const int lane = gid & 63;
        const int quad = lane >> 4, t15 = lane & 15;
        const float* src = k + ((size_t)bh * S_LEN + tile * 16 + t15) * D_DIM
                             + ch * 32 + quad * 8;
        float x[8];
        *(float4*)(x + 0) = *(const float4*)(src);
        *(float4*)(x + 4) = *(const float4*)(src + 4);
        ushort_t hv[8];
        #pragma unroll
        for (int i = 0; i < 8; ++i) hv[i] = f16bits(x[i] * 0.125f);
        *(short4v*)(kh + (size_t)gid * 8)     = *(short4v*)(hv);
        *(short4v*)(kh + (size_t)gid * 8 + 4) = *(short4v*)(hv + 4);
    } else if (bx < 768) {
        const int bi = bx - 512;
        const int tt = bi & 15, bh = bi >> 4;
        const float* vb = v + ((size_t)bh * S_LEN + tt * 64) * D_DIM;
        #pragma unroll
        for (int p = 0; p < 4; ++p) {
            int idx = p * 1024 + tid * 4;
            int r = idx >> 6, c = idx & 63;
            float4 x = *(const float4*)(vb + r * 64 + c);
            Ls[r][c] = x.x; Ls[r][c+1] = x.y; Ls[r][c+2] = x.z; Ls[r][c+3] = x.w;
        }
        __syncthreads();
        const int d = tid >> 2, c0 = (tid & 3) * 16;
        ushort_t hi[16];
        #pragma unroll
        for (int j = 0; j < 16; ++j) hi[j] = f16bits(Ls[c0 + j][d]);
        const int tb0 = tt * 8 + (c0 >> 3);
        const size_t o0 = (((size_t)bh * 128 + tb0) * 64 + d) * 8;
        const size_t o1 = (((size_t)bh * 128 + tb0 + 1) * 64 + d) * 8;
        *(short4v*)(vh + o0)     = *(short4v*)(hi);
        *(short4v*)(vh + o0 + 4) = *(short4v*)(hi + 4);
        *(short4v*)(vh + o1)     = *(short4v*)(hi + 8);
        *(short4v*)(vh + o1 + 4) = *(short4v*)(hi + 12);
    } else {
        const int gid = (bx - 768) * 256 + tid;    // 0..65535
        const int row = gid >> 5, wd = gid & 31;   // row = b*1024+s
        const int4* mp = (const int4*)(mask + (size_t)row * 1024 + wd * 32);
        unsigned bits = 0;
        #pragma unroll
        for (int p = 0; p < 8; ++p) {
            int4 qv = mp[p];
            bits |= (qv.x != 0 ? 1u : 0u) << (p * 4 + 0);
            bits |= (qv.y != 0 ? 1u : 0u) << (p * 4 + 1);
            bits |= (qv.z != 0 ? 1u : 0u) << (p * 4 + 2);
            bits |= (qv.w != 0 ? 1u : 0u) << (p * 4 + 3);
        }
        mw[(size_t)row * 32 + wd] = bits;
    }
}

// ---------- Fused (RPB=14, f16, in-place P): QK^T -> conv -> PV --------------
// grid (74 s-tiles, 16 bh), block 512 = 8 waves. LDS ~38.8 KB.
// Phase A: 8 waves x 8 K-tiles; ONE 16-row f16 A-set (rows s0-1+m, K prescaled
//          by 1/8 in prep). dpH: col t at idx t+2, pads zeroed.
// Phase B: scalar conv with PACKED f16 window (6 rows x 4 u32) and half-
//          extraction AT THE FMA USE SITE -> backend forms v_fma_mix_f32
//          (f16 src x f32 weight + f32 acc), eliminating the 72 v_cvt/thread;
//          worst case the fpexts CSE back to R1's exact code. Bias folded
//          into the first tap (acc = fma(w00, x, cb)). Leaky-relu in
//          0.505x+0.495|x| form; log2(e) folded into aF/bF/lb so exp is a
//          bare v_exp_f32. Row-sum computed in Phase C by MFMA (not here).
// Phase C: PV reads P from dpH; SECOND accumulator vs all-ones B fragment
//          gives row sums; th=0 partial via lsRow[16], th=1 waves add theirs.
#define DPSTR 1040  // dp/P row stride (halfs)
__global__ __launch_bounds__(512) void fused_qk_conv_av(
    const float* __restrict__ q,
    const ushort_t* __restrict__ kh, const unsigned* __restrict__ mw,
    const ushort_t* __restrict__ vh,
    const float* __restrict__ conv_w, const float* __restrict__ conv_b,
    const float* __restrict__ lin_w, const float* __restrict__ lin_b,
    float* __restrict__ out)
{
    __shared__ ushort_t dpH[16 * DPSTR];   // 33.3 KB; dp in A/B, P in C
    __shared__ float oBuf[16][68];         // 4.35 KB
    __shared__ float lsRow[16];            // 64 B (th=0 rowsum partials)
    __shared__ unsigned mb[16][32];        // 2 KB

    const int st = blockIdx.x, bh = blockIdx.y;
    const int s0 = st * RPB;
    const int b  = bh >> 3;
    const int tid = threadIdx.x;
    const int wave = tid >> 6, lane = tid & 63;
    const int m = lane & 15, quad = lane >> 4;

    // mask bits -> LDS (one word per thread; row o <-> s = s0-1+o)
    {
        const int o = tid >> 5, wd = tid & 31;
        const int s = s0 - 1 + o;
        mb[o][wd] = (s >= 0 && s < S_LEN)
                  ? mw[((size_t)b * S_LEN + s) * 32 + wd] : 0u;
    }
    // zero dpH pads: idx 0,1 (t=-2,-1) and 1026,1027 (t=1024,1025) per row
    if (tid < 64) {
        const int row = tid >> 2, i = tid & 3;
        const int idx = (i < 2) ? i : 1024 + i;
        dpH[row * DPSTR + idx] = 0;
    }

    // ---------------- Phase A: QK into LDS (single f16 A-set) ---------------
    const int sA = s0 - 1 + m;
    const int sQ = sA < 0 ? 0 : (sA > S_LEN - 1 ? S_LEN - 1 : sA);
    const float* qp = q + ((size_t)bh * S_LEN + sQ) * D_DIM + quad * 8;
    float qa[16];
    *(float4*)(qa + 0)  = *(const float4*)(qp + 0);
    *(float4*)(qa + 4)  = *(const float4*)(qp + 4);
    *(float4*)(qa + 8)  = *(const float4*)(qp + 32);
    *(float4*)(qa + 12) = *(const float4*)(qp + 36);
    half8 AH0, AH1;
    #pragma unroll
    for (int i = 0; i < 8; ++i) {
        AH0[i] = (_Float16)qa[i];          // 1/8 scale lives in kh now
        AH1[i] = (_Float16)qa[8 + i];
    }

    #pragma unroll
    for (int tt = 0; tt < 8; ++tt) {
        const int tile = wave * 8 + tt;
        const size_t kb = (((size_t)bh * 64 + tile) * 128 + lane) * 8;
        half8 KH0 = *(const half8*)(kh + kb);
        half8 KH1 = *(const half8*)(kh + kb + 512);
        f32x4 a = {0.f, 0.f, 0.f, 0.f};
        a = __builtin_amdgcn_mfma_f32_16x16x32_f16(AH0, KH0, a, 0, 0, 0);
        a = __builtin_amdgcn_mfma_f32_16x16x32_f16(AH1, KH1, a, 0, 0, 0);
        const int col = tile * 16 + m;
        #pragma unroll
        for (int r = 0; r < 4; ++r) {
            const int row = quad * 4 + r;
            const int s = s0 - 1 + row;
            const float v = (s >= 0 && s < S_LEN) ? a[r] : 0.f;
            dpH[row * DPSTR + col + 2] = f16bits(v);
        }
    }

    // hoisted uniform coefficients (SGPR via readfirstlane / uniform loads)
    float w[36];
    #pragma unroll
    for (int i = 0; i < 36; ++i) w[i] = conv_w[i];
    const float L2E = 1.44269504088896341f;
    float cb[4], aF[4], bF[4];
    #pragma unroll
    for (int f = 0; f < 4; ++f) {
        cb[f] = conv_b[f];
        const float lwf = lin_w[f];
        aF[f] = uniform_f(0.505f * lwf * L2E);   // lr(x)=0.505x+0.495|x|
        bF[f] = uniform_f(0.495f * lwf * L2E);
    }
    const float lbE = uniform_f(lin_b[0] * L2E);

    __syncthreads();

    // ---------------- Phase B: conv + mask + exp2 (P held in registers) -----
    const int rh = tid >> 8, cg = tid & 255, c0 = cg * 4;
    uint2 Ps[8];           // packed f16 P: [pass*4 + jo]
    #pragma unroll
    for (int pass = 0; pass < 2; ++pass) {
        const int obase = rh * 8 + pass * 4;        // first of 4 output rows
        // packed window: row jj, halfs t = c0-2 .. c0+5 (8 halfs = 4 u32)
        union WU { uint2 u2[2]; h2 hh[4]; } wr[6];
        #pragma unroll
        for (int jj = 0; jj < 6; ++jj) {
            const int dr = obase - 1 + jj;          // -1..16
            if (dr >= 0 && dr < 16) {
                const ushort_t* rp = &dpH[dr * DPSTR + c0];
                wr[jj].u2[0] = *(const uint2*)rp;        // t: c0-2..c0+1
                wr[jj].u2[1] = *(const uint2*)(rp + 4);  // t: c0+2..c0+5
            } else {
                wr[jj].u2[0] = (uint2){0u, 0u};
                wr[jj].u2[1] = (uint2){0u, 0u};
            }
        }
        // XV(jj, p): window value at t = c0-1+p  (p = c+dc in 0..5)
        #define XV(jj, p) ((float)wr[jj].hh[((p) + 1) >> 1][((p) + 1) & 1])
        #pragma unroll
        for (int jo = 0; jo < 4; ++jo) {
            const int o = obase + jo;               // wave-uniform guard
            const bool act = (o >= 1) && (o <= RPB) && (s0 - 1 + o < S_LEN);
            if (act) {
                float pr[4] = {lbE, lbE, lbE, lbE}; // pre-attn * log2(e)
                #pragma unroll
                for (int f = 0; f < 4; ++f) {
                    const float* wf = w + f * 9;
                    float acc[4];
                    const float w00 = wf[0];        // first tap: bias folded
                    const float cbf = cb[f];
                    #pragma unroll
                    for (int c = 0; c < 4; ++c)
                        acc[c] = fmaf(w00, XV(jo, c), cbf);
                    #pragma unroll
                    for (int t = 1; t < 9; ++t) {
                        const int dr = t / 3, dc = t % 3;
                        const float wt = wf[t];
                        #pragma unroll
                        for (int c = 0; c < 4; ++c)
                            acc[c] = fmaf(wt, XV(jo + dr, c + dc), acc[c]);
                    }
                    const float af = aF[f], bf = bF[f];
                    #pragma unroll
                    for (int c = 0; c < 4; ++c) {
                        pr[c] = fmaf(af, acc[c], pr[c]);
                        pr[c] = fmaf(bf, fabsf(acc[c]), pr[c]); // abs = mod
                    }
                }
                const unsigned word = mb[o][cg >> 3];
                const unsigned nib  = (word >> ((cg & 7) * 4)) & 0xFu;
                float pv[4];
                #pragma unroll
                for (int c = 0; c < 4; ++c) {
                    const float pe = ((nib >> c) & 1u) ? pr[c] : -1e30f;
                    pv[c] = fast_exp2(pe);          // exp(pre) == 2^(pre*L2E)
                }
                Ps[pass * 4 + jo].x =
                    (uint_t)f16bits(pv[0]) | ((uint_t)f16bits(pv[1]) << 16);
                Ps[pass * 4 + jo].y =
                    (uint_t)f16bits(pv[2]) | ((uint_t)f16bits(pv[3]) << 16);
            } else {
                Ps[pass * 4 + jo].x = 0u;
                Ps[pass * 4 + jo].y = 0u;
            }
        }
        #undef XV
    }
    __syncthreads();   // all dp reads done -> safe to overwrite dpH with P

    // write P in place over dpH (col t at idx t)
    #pragma unroll
    for (int i = 0; i < 8; ++i) {
        const int o = rh * 8 + i;
        *(uint2*)&dpH[o * DPSTR + c0] = Ps[i];
    }
    __syncthreads();

    // ---------------- Phase C: PV + MFMA row sums ---------------------------
    const int d0 = (wave & 3) * 16;
    const int th = wave >> 2;
    f32x4 O  = {0.f, 0.f, 0.f, 0.f};
    f32x4 RS = {0.f, 0.f, 0.f, 0.f};
    half8 ONE;
    #pragma unroll
    for (int i = 0; i < 8; ++i) ONE[i] = (_Float16)1.0f;
    const ushort_t* ph_base = &dpH[m * DPSTR + th * 512 + quad * 8];
    const ushort_t* vv_base = vh + ((size_t)bh * 65536
                                    + (size_t)(th * 64 + quad) * 512
                                    + (size_t)(d0 + m) * 8);
    #pragma unroll 4
    for (int i = 0; i < 16; ++i) {
        half8 ph = *(const half8*)(ph_base + i * 32);
        half8 vv = *(const half8*)(vv_base + (size_t)i * 2048);
        O  = __builtin_amdgcn_mfma_f32_16x16x32_f16(ph, vv, O, 0, 0, 0);
        RS = __builtin_amdgcn_mfma_f32_16x16x32_f16(ph, ONE, RS, 0, 0, 0);
    }
    if (wave < 4) {
        #pragma unroll
        for (int r = 0; r < 4; ++r) oBuf[quad * 4 + r][d0 + m] = O[r];
    }
    if (wave == 0 && m == 0) {   // lanes 0,16,32,48: publish th=0 partials
        #pragma unroll
        for (int r = 0; r < 4; ++r) lsRow[quad * 4 + r] = RS[r];
    }
    __syncthreads();
    if (wave >= 4) {
        #pragma unroll
        for (int r = 0; r < 4; ++r) {
            const int br = quad * 4 + r;
            const int s = s0 - 1 + br;
            if (br >= 1 && br <= RPB && s < S_LEN) {
                const float lsum = lsRow[br] + RS[r];
                out[((size_t)bh * S_LEN + s) * D_DIM + d0 + m] =
                    (O[r] + oBuf[br][d0 + m]) / lsum;
            }
        }
    }
}

extern "C" void kernel_launch(void* const* d_in, const int* in_sizes, int n_in,
                              void* d_out, int out_size, void* d_ws, size_t ws_size,
                              hipStream_t stream) {
    const float* q      = (const float*)d_in[0];
    const float* k      = (const float*)d_in[1];
    const float* v      = (const float*)d_in[2];
    const int*   mask   = (const int*)d_in[3];
    const float* conv_w = (const float*)d_in[4];
    const float* conv_b = (const float*)d_in[5];
    const float* lin_w  = (const float*)d_in[6];
    const float* lin_b  = (const float*)d_in[7];
    float* out = (float*)d_out;

    char* wsb = (char*)d_ws;
    const size_t MB = 1024 * 1024;
    ushort_t* kh = (ushort_t*)(wsb + 0 * MB);     // 2 MiB
    ushort_t* vh = (ushort_t*)(wsb + 2 * MB);     // 2 MiB
    unsigned* mw = (unsigned*)(wsb + 4 * MB);     // 256 KiB

    prep<<<dim3(1024), 256, 0, stream>>>(k, v, mask, kh, vh, mw);
    fused_qk_conv_av<<<dim3(NSB, NBH), 512, 0, stream>>>(
        q, kh, mw, vh, conv_w, conv_b, lin_w, lin_b, out);
}

// Round 9
// 117.913 us; speedup vs baseline: 1.1250x; 1.0009x over previous
//
#include <hip/hip_runtime.h>
#include <math.h>

#define S_LEN 1024
#define D_DIM 64
#define NBH   16
#define RPB   14
#define NSB   74           // ceil(1024/14)

typedef unsigned short ushort_t;
typedef unsigned int uint_t;
typedef __attribute__((ext_vector_type(8))) _Float16 half8;  // 8 f16 (4 VGPRs)
typedef __attribute__((ext_vector_type(2))) _Float16 h2;
typedef __attribute__((ext_vector_type(4))) short short4v;   // 8 B
typedef __attribute__((ext_vector_type(4))) float f32x4;

__device__ __forceinline__ ushort_t f16bits(float x) {
    _Float16 h = (_Float16)x;                 // RNE
    ushort_t b;
    __builtin_memcpy(&b, &h, 2);
    return b;
}
__device__ __forceinline__ float uniform_f(float x) {
    return __int_as_float(__builtin_amdgcn_readfirstlane(__float_as_int(x)));
}
__device__ __forceinline__ float fast_exp2(float x) {
#if __has_builtin(__builtin_amdgcn_exp2f)
    return __builtin_amdgcn_exp2f(x);         // v_exp_f32 (2^x)
#else
    return exp2f(x);
#endif
}
// One conv tap in ONE instruction: acc += f16half(xp) * w  (f32 accum, f32 w).
// Bit-identical to fmaf((float)h, w, acc): f16->f32 conversion is exact.
// hi is compile-time constant after unrolling -> dead branch folds.
__device__ __forceinline__ float fmamix(int hi, uint_t xp, float w, float acc) {
    if (hi)
        asm("v_fma_mix_f32 %0, %1, %2, %0 op_sel:[1,0,0] op_sel_hi:[1,0,0]"
            : "+v"(acc) : "v"(xp), "s"(w));
    else
        asm("v_fma_mix_f32 %0, %1, %2, %0 op_sel:[0,0,0] op_sel_hi:[1,0,0]"
            : "+v"(acc) : "v"(xp), "s"(w));
    return acc;
}
// Same, but fresh accumulator from a third operand (bias fold for tap 0).
__device__ __forceinline__ float fmamix3(int hi, uint_t xp, float w, float c) {
    float d;
    if (hi)
        asm("v_fma_mix_f32 %0, %1, %2, %3 op_sel:[1,0,0] op_sel_hi:[1,0,0]"
            : "=v"(d) : "v"(xp), "s"(w), "v"(c));
    else
        asm("v_fma_mix_f32 %0, %1, %2, %3 op_sel:[0,0,0] op_sel_hi:[1,0,0]"
            : "=v"(d) : "v"(xp), "s"(w), "v"(c));
    return d;
}

// ------------------------------ Prep (unchanged from R8) ---------------------
// blocks [0,512):    K * 0.125 -> f16 QK B-frag tiled layout (16B stores)
// blocks [512,768):  V transpose -> f16 PV B-frag tiled layout
// blocks [768,1024): mask bit-pack, thread-per-word
__global__ __launch_bounds__(256) void prep(
    const float* __restrict__ k, const float* __restrict__ v,
    const int* __restrict__ mask,
    ushort_t* __restrict__ kh, ushort_t* __restrict__ vh,
    unsigned* __restrict__ mw)
{
    __shared__ float Ls[64][65];
    const int tid = threadIdx.x;
    const int bx = blockIdx.x;
    if (bx < 512) {
        const int gid  = bx * 256 + tid;          // 0..131071
        const int bh   = gid >> 13;
        const int tile = (gid >> 7) & 63;
        const int ch   = (gid >> 6) & 1;
        const int lane = gid & 63;
        const int quad = lane >> 4, t15 = lane & 15;
        const float* src = k + ((size_t)bh * S_LEN + tile * 16 + t15) * D_DIM
                             + ch * 32 + quad * 8;
        float x[8];
        *(float4*)(x + 0) = *(const float4*)(src);
        *(float4*)(x + 4) = *(const float4*)(src + 4);
        ushort_t hv[8];
        #pragma unroll
        for (int i = 0; i < 8; ++i) hv[i] = f16bits(x[i] * 0.125f);
        *(short4v*)(kh + (size_t)gid * 8)     = *(short4v*)(hv);
        *(short4v*)(kh + (size_t)gid * 8 + 4) = *(short4v*)(hv + 4);
    } else if (bx < 768) {
        const int bi = bx - 512;
        const int tt = bi & 15, bh = bi >> 4;
        const float* vb = v + ((size_t)bh * S_LEN + tt * 64) * D_DIM;
        #pragma unroll
        for (int p = 0; p < 4; ++p) {
            int idx = p * 1024 + tid * 4;
            int r = idx >> 6, c = idx & 63;
            float4 x = *(const float4*)(vb + r * 64 + c);
            Ls[r][c] = x.x; Ls[r][c+1] = x.y; Ls[r][c+2] = x.z; Ls[r][c+3] = x.w;
        }
        __syncthreads();
        const int d = tid >> 2, c0 = (tid & 3) * 16;
        ushort_t hi[16];
        #pragma unroll
        for (int j = 0; j < 16; ++j) hi[j] = f16bits(Ls[c0 + j][d]);
        const int tb0 = tt * 8 + (c0 >> 3);
        const size_t o0 = (((size_t)bh * 128 + tb0) * 64 + d) * 8;
        const size_t o1 = (((size_t)bh * 128 + tb0 + 1) * 64 + d) * 8;
        *(short4v*)(vh + o0)     = *(short4v*)(hi);
        *(short4v*)(vh + o0 + 4) = *(short4v*)(hi + 4);
        *(short4v*)(vh + o1)     = *(short4v*)(hi + 8);
        *(short4v*)(vh + o1 + 4) = *(short4v*)(hi + 12);
    } else {
        const int gid = (bx - 768) * 256 + tid;    // 0..65535
        const int row = gid >> 5, wd = gid & 31;   // row = b*1024+s
        const int4* mp = (const int4*)(mask + (size_t)row * 1024 + wd * 32);
        unsigned bits = 0;
        #pragma unroll
        for (int p = 0; p < 8; ++p) {
            int4 qv = mp[p];
            bits |= (qv.x != 0 ? 1u : 0u) << (p * 4 + 0);
            bits |= (qv.y != 0 ? 1u : 0u) << (p * 4 + 1);
            bits |= (qv.z != 0 ? 1u : 0u) << (p * 4 + 2);
            bits |= (qv.w != 0 ? 1u : 0u) << (p * 4 + 3);
        }
        mw[(size_t)row * 32 + wd] = bits;
    }
}

// ---------- Fused (RPB=14, f16, in-place P): QK^T -> conv -> PV --------------
// grid (74 s-tiles, 16 bh), block 512 = 8 waves. LDS ~38.8 KB.
// Phase A: 8 waves x 8 K-tiles; ONE 16-row f16 A-set. dpH: col t at idx t+2.
// Phase B: conv via FORCED v_fma_mix_f32 (inline asm): one instruction per
//          tap, f16 source half selected by op_sel, f32 weight in SGPR, f32
//          accumulate. No cvt, no extraction (R8's fold bet didn't form it).
//          Window stays packed: 6 rows x 4 u32. Bias folded into tap 0's
//          src2. Leaky-relu 0.505x+0.495|x| (abs = modifier); log2(e) folded
//          so exp is bare v_exp_f32. Row-sum via Phase-C MFMA.
// Phase C: PV reads P from dpH; all-ones B-frag MFMA gives row sums.
#define DPSTR 1040  // dp/P row stride (halfs)
__global__ __launch_bounds__(512) void fused_qk_conv_av(
    const float* __restrict__ q,
    const ushort_t* __restrict__ kh, const unsigned* __restrict__ mw,
    const ushort_t* __restrict__ vh,
    const float* __restrict__ conv_w, const float* __restrict__ conv_b,
    const float* __restrict__ lin_w, const float* __restrict__ lin_b,
    float* __restrict__ out)
{
    __shared__ ushort_t dpH[16 * DPSTR];   // 33.3 KB; dp in A/B, P in C
    __shared__ float oBuf[16][68];         // 4.35 KB
    __shared__ float lsRow[16];            // 64 B (th=0 rowsum partials)
    __shared__ unsigned mb[16][32];        // 2 KB

    const int st = blockIdx.x, bh = blockIdx.y;
    const int s0 = st * RPB;
    const int b  = bh >> 3;
    const int tid = threadIdx.x;
    const int wave = tid >> 6, lane = tid & 63;
    const int m = lane & 15, quad = lane >> 4;

    // mask bits -> LDS (one word per thread; row o <-> s = s0-1+o)
    {
        const int o = tid >> 5, wd = tid & 31;
        const int s = s0 - 1 + o;
        mb[o][wd] = (s >= 0 && s < S_LEN)
                  ? mw[((size_t)b * S_LEN + s) * 32 + wd] : 0u;
    }
    // zero dpH pads: idx 0,1 (t=-2,-1) and 1026,1027 (t=1024,1025) per row
    if (tid < 64) {
        const int row = tid >> 2, i = tid & 3;
        const int idx = (i < 2) ? i : 1024 + i;
        dpH[row * DPSTR + idx] = 0;
    }

    // ---------------- Phase A: QK into LDS (single f16 A-set) ---------------
    const int sA = s0 - 1 + m;
    const int sQ = sA < 0 ? 0 : (sA > S_LEN - 1 ? S_LEN - 1 : sA);
    const float* qp = q + ((size_t)bh * S_LEN + sQ) * D_DIM + quad * 8;
    float qa[16];
    *(float4*)(qa + 0)  = *(const float4*)(qp + 0);
    *(float4*)(qa + 4)  = *(const float4*)(qp + 4);
    *(float4*)(qa + 8)  = *(const float4*)(qp + 32);
    *(float4*)(qa + 12) = *(const float4*)(qp + 36);
    half8 AH0, AH1;
    #pragma unroll
    for (int i = 0; i < 8; ++i) {
        AH0[i] = (_Float16)qa[i];          // 1/8 scale lives in kh now
        AH1[i] = (_Float16)qa[8 + i];
    }

    #pragma unroll
    for (int tt = 0; tt < 8; ++tt) {
        const int tile = wave * 8 + tt;
        const size_t kb = (((size_t)bh * 64 + tile) * 128 + lane) * 8;
        half8 KH0 = *(const half8*)(kh + kb);
        half8 KH1 = *(const half8*)(kh + kb + 512);
        f32x4 a = {0.f, 0.f, 0.f, 0.f};
        a = __builtin_amdgcn_mfma_f32_16x16x32_f16(AH0, KH0, a, 0, 0, 0);
        a = __builtin_amdgcn_mfma_f32_16x16x32_f16(AH1, KH1, a, 0, 0, 0);
        const int col = tile * 16 + m;
        #pragma unroll
        for (int r = 0; r < 4; ++r) {
            const int row = quad * 4 + r;
            const int s = s0 - 1 + row;
            const float v = (s >= 0 && s < S_LEN) ? a[r] : 0.f;
            dpH[row * DPSTR + col + 2] = f16bits(v);
        }
    }

    // hoisted uniform coefficients
    float w[36];
    #pragma unroll
    for (int i = 0; i < 36; ++i) w[i] = conv_w[i];
    const float L2E = 1.44269504088896341f;
    float cbV[4], aF[4], bF[4];
    #pragma unroll
    for (int f = 0; f < 4; ++f) {
        cbV[f] = conv_b[f];                      // used as VGPR src2 of tap 0
        const float lwf = lin_w[f];
        aF[f] = uniform_f(0.505f * lwf * L2E);   // lr(x)=0.505x+0.495|x|
        bF[f] = uniform_f(0.495f * lwf * L2E);
    }
    const float lbE = uniform_f(lin_b[0] * L2E);

    __syncthreads();

    // ---------------- Phase B: conv (v_fma_mix) + mask + exp2 ---------------
    const int rh = tid >> 8, cg = tid & 255, c0 = cg * 4;
    uint2 Ps[8];           // packed f16 P: [pass*4 + jo]
    #pragma unroll
    for (int pass = 0; pass < 2; ++pass) {
        const int obase = rh * 8 + pass * 4;        // first of 4 output rows
        // packed window: row jj, halfs t = c0-2 .. c0+5 (8 halfs = 4 u32)
        uint_t wrw[6][4];
        #pragma unroll
        for (int jj = 0; jj < 6; ++jj) {
            const int dr = obase - 1 + jj;          // -1..16
            if (dr >= 0 && dr < 16) {
                const ushort_t* rp = &dpH[dr * DPSTR + c0];
                const uint2 rA = *(const uint2*)rp;        // t: c0-2..c0+1
                const uint2 rB = *(const uint2*)(rp + 4);  // t: c0+2..c0+5
                wrw[jj][0] = rA.x; wrw[jj][1] = rA.y;
                wrw[jj][2] = rB.x; wrw[jj][3] = rB.y;
            } else {
                wrw[jj][0] = 0u; wrw[jj][1] = 0u;
                wrw[jj][2] = 0u; wrw[jj][3] = 0u;
            }
        }
        // window value at t = c0-1+p lives in word (p+1)>>1, half (p+1)&1
        #pragma unroll
        for (int jo = 0; jo < 4; ++jo) {
            const int o = obase + jo;               // wave-uniform guard
            const bool act = (o >= 1) && (o <= RPB) && (s0 - 1 + o < S_LEN);
            if (act) {
                float pr[4] = {lbE, lbE, lbE, lbE}; // pre-attn * log2(e)
                #pragma unroll
                for (int f = 0; f < 4; ++f) {
                    const float* wf = w + f * 9;
                    const float cbf = cbV[f];
                    float acc[4];
                    // tap 0 (dr=0,dc=0): fresh acc with bias as src2
                    #pragma unroll
                    for (int c = 0; c < 4; ++c) {
                        const int idx = c + 1;
                        acc[c] = fmamix3(idx & 1, wrw[jo][idx >> 1],
                                         wf[0], cbf);
                    }
                    // taps 1..8: in-place mix fma, one instruction each
                    #pragma unroll
                    for (int t = 1; t < 9; ++t) {
                        const int dr = t / 3, dc = t % 3;
                        #pragma unroll
                        for (int c = 0; c < 4; ++c) {
                            const int idx = c + dc + 1;
                            acc[c] = fmamix(idx & 1, wrw[jo + dr][idx >> 1],
                                            wf[t], acc[c]);
                        }
                    }
                    const float af = aF[f], bf = bF[f];
                    #pragma unroll
                    for (int c = 0; c < 4; ++c) {
                        pr[c] = fmaf(af, acc[c], pr[c]);
                        pr[c] = fmaf(bf, fabsf(acc[c]), pr[c]); // abs = mod
                    }
                }
                const unsigned word = mb[o][cg >> 3];
                const unsigned nib  = (word >> ((cg & 7) * 4)) & 0xFu;
                float pv[4];
                #pragma unroll
                for (int c = 0; c < 4; ++c) {
                    const float pe = ((nib >> c) & 1u) ? pr[c] : -1e30f;
                    pv[c] = fast_exp2(pe);          // exp(pre) == 2^(pre*L2E)
                }
                Ps[pass * 4 + jo].x =
                    (uint_t)f16bits(pv[0]) | ((uint_t)f16bits(pv[1]) << 16);
                Ps[pass * 4 + jo].y =
                    (uint_t)f16bits(pv[2]) | ((uint_t)f16bits(pv[3]) << 16);
            } else {
                Ps[pass * 4 + jo].x = 0u;
                Ps[pass * 4 + jo].y = 0u;
            }
        }
    }
    __syncthreads();   // all dp reads done -> safe to overwrite dpH with P

    // write P in place over dpH (col t at idx t)
    #pragma unroll
    for (int i = 0; i < 8; ++i) {
        const int o = rh * 8 + i;
        *(uint2*)&dpH[o * DPSTR + c0] = Ps[i];
    }
    __syncthreads();

    // ---------------- Phase C: PV + MFMA row sums ---------------------------
    const int d0 = (wave & 3) * 16;
    const int th = wave >> 2;
    f32x4 O  = {0.f, 0.f, 0.f, 0.f};
    f32x4 RS = {0.f, 0.f, 0.f, 0.f};
    half8 ONE;
    #pragma unroll
    for (int i = 0; i < 8; ++i) ONE[i] = (_Float16)1.0f;
    const ushort_t* ph_base = &dpH[m * DPSTR + th * 512 + quad * 8];
    const ushort_t* vv_base = vh + ((size_t)bh * 65536
                                    + (size_t)(th * 64 + quad) * 512
                                    + (size_t)(d0 + m) * 8);
    #pragma unroll 4
    for (int i = 0; i < 16; ++i) {
        half8 ph = *(const half8*)(ph_base + i * 32);
        half8 vv = *(const half8*)(vv_base + (size_t)i * 2048);
        O  = __builtin_amdgcn_mfma_f32_16x16x32_f16(ph, vv, O, 0, 0, 0);
        RS = __builtin_amdgcn_mfma_f32_16x16x32_f16(ph, ONE, RS, 0, 0, 0);
    }
    if (wave < 4) {
        #pragma unroll
        for (int r = 0; r < 4; ++r) oBuf[quad * 4 + r][d0 + m] = O[r];
    }
    if (wave == 0 && m == 0) {   // lanes 0,16,32,48: publish th=0 partials
        #pragma unroll
        for (int r = 0; r < 4; ++r) lsRow[quad * 4 + r] = RS[r];
    }
    __syncthreads();
    if (wave >= 4) {
        #pragma unroll
        for (int r = 0; r < 4; ++r) {
            const int br = quad * 4 + r;
            const int s = s0 - 1 + br;
            if (br >= 1 && br <= RPB && s < S_LEN) {
                const float lsum = lsRow[br] + RS[r];
                out[((size_t)bh * S_LEN + s) * D_DIM + d0 + m] =
                    (O[r] + oBuf[br][d0 + m]) / lsum;
            }
        }
    }
}

extern "C" void kernel_launch(void* const* d_in, const int* in_sizes, int n_in,
                              void* d_out, int out_size, void* d_ws, size_t ws_size,
                              hipStream_t stream) {
    const float* q      = (const float*)d_in[0];
    const float* k      = (const float*)d_in[1];
    const float* v      = (const float*)d_in[2];
    const int*   mask   = (const int*)d_in[3];
    const float* conv_w = (const float*)d_in[4];
    const float* conv_b = (const float*)d_in[5];
    const float* lin_w  = (const float*)d_in[6];
    const float* lin_b  = (const float*)d_in[7];
    float* out = (float*)d_out;

    char* wsb = (char*)d_ws;
    const size_t MB = 1024 * 1024;
    ushort_t* kh = (ushort_t*)(wsb + 0 * MB);     // 2 MiB
    ushort_t* vh = (ushort_t*)(wsb + 2 * MB);     // 2 MiB
    unsigned* mw = (unsigned*)(wsb + 4 * MB);     // 256 KiB

    prep<<<dim3(1024), 256, 0, stream>>>(k, v, mask, kh, vh, mw);
    fused_qk_conv_av<<<dim3(NSB, NBH), 512, 0, stream>>>(
        q, kh, mw, vh, conv_w, conv_b, lin_w, lin_b, out);
}